// Round 4
// baseline (845.173 us; speedup 1.0000x reference)
//
#include <hip/hip_runtime.h>

#define D    780   // binom(40,2)
#define NG   39    // gates
#define NP   38    // real rotation pairs per gate
#define NPP  48    // padded to 3 iterations x 16 pairs
#define KT   16    // vectors (columns) per tile
#define ROWS 800   // 780 + 20 scratch rows for pad pairs

struct Tbl { unsigned v[NG][NPP]; };

constexpr int cpair(int p, int q) { return p * (79 - p) / 2 + (q - p - 1); }

constexpr Tbl make_tbl() {
  Tbl t{};
  for (int g = 0; g < NG; ++g)
    for (int p = 0; p < NPP; ++p) {
      int i, j;
      if (p < NP) {
        const int cc = (p < g) ? p : p + 2;      // companion qubit, skips g,g+1
        const int g1 = g + 1;
        const int a0 = (g  < cc) ? g  : cc,  a1 = (g  < cc) ? cc : g;
        const int b0 = (g1 < cc) ? g1 : cc,  b1 = (g1 < cc) ? cc : g1;
        i = cpair(a0, a1);                        // state containing qubit g
        j = cpair(b0, b1);                        // state containing qubit g+1
      } else {                                    // pad: distinct scratch rows,
        i = D + (p - NP);                         // mixed parity for bank balance
        j = D + 10 + (p - NP);
      }
      t.v[g][p] = ((unsigned)(j * KT) << 16) | (unsigned)(i * KT);
    }
  return t;
}

__device__ __constant__ Tbl g_tbl = make_tbl();

// Apply all 39 gates to the wave-owned tile[ROWS][KT] (16 vectors, element r
// of vector k at tile[r*KT+k]). Lane = (pair-slot pq = l>>2, quad q = l&3).
// Per gate: 3 iterations x {1 const-mem u32, 2 ds_read_b128, 2 ds_write_b128}.
// Pairs within a gate are disjoint (pads use scratch rows); cross-gate order
// is guaranteed by per-wave in-order DS ops.
__device__ __forceinline__ void run_chain(float* __restrict__ t,
                                          const float* __restrict__ ang,
                                          int lane) {
  float vc = 1.0f, vs = 0.0f;
  if (lane < NG) sincosf(ang[lane], &vs, &vc);   // lane g holds (cos,sin) of gate g
  const int pq = lane >> 2;
  const int q4 = (lane & 3) * 4;

  #pragma unroll 1
  for (int g = 0; g < NG; ++g) {
    const float c = __int_as_float(__builtin_amdgcn_readlane(__float_as_int(vc), g));
    const float s = __int_as_float(__builtin_amdgcn_readlane(__float_as_int(vs), g));
    const unsigned* tg = g_tbl.v[g];
    #pragma unroll
    for (int it = 0; it < 3; ++it) {
      const unsigned pk = tg[it * 16 + pq];      // broadcast within quad, L1-hot
      const int fi = (int)(pk & 0xffffu) + q4;   // i*16 + 4q  (float index)
      const int fj = (int)(pk >> 16) + q4;
      float4 vi = *(const float4*)(t + fi);      // ds_read_b128, bank-balanced
      float4 vj = *(const float4*)(t + fj);
      float4 ni, nj;
      ni.x = c * vi.x - s * vj.x;  nj.x = s * vi.x + c * vj.x;
      ni.y = c * vi.y - s * vj.y;  nj.y = s * vi.y + c * vj.y;
      ni.z = c * vi.z - s * vj.z;  nj.z = s * vi.z + c * vj.z;
      ni.w = c * vi.w - s * vj.w;  nj.w = s * vi.w + c * vj.w;
      *(float4*)(t + fi) = ni;
      *(float4*)(t + fj) = nj;
    }
    __builtin_amdgcn_wave_barrier();
  }
}

// Phase A: out[R,:] = V * rho[R,:] over the column axis. Tile = 16 matrix rows,
// stored transposed in LDS ([element c][row r]) so the chain runs b128 over rows.
// Scalar b32 staging: bank = 16*(c&1) + r -> 2-way (free).
__global__ __launch_bounds__(64) void rbs_rows(const float* __restrict__ rho,
                                               const float* __restrict__ ang,
                                               float* __restrict__ out) {
  __shared__ float tile[ROWS * KT];              // 51,200 B -> 3 blocks/CU
  const int l = threadIdx.x;
  const size_t mat = (size_t)blockIdx.y * D * D;
  const int r = l & 15, cg = l >> 4;             // r: tile row, cg: col group
  const int R = blockIdx.x * KT + r;             // matrix row

  if (R < D) {
    const float* row = rho + mat + (size_t)R * D;
    #pragma unroll 4
    for (int m = 0; m < 195; ++m) {              // c = cg + 4m covers 0..779
      const int c = cg + 4 * m;
      tile[c * KT + r] = row[c];
    }
  }
  __syncthreads();
  run_chain(tile, ang, l);
  __syncthreads();
  if (R < D) {
    float* row = out + mat + (size_t)R * D;
    #pragma unroll 4
    for (int m = 0; m < 195; ++m) {
      const int c = cg + 4 * m;
      row[c] = tile[c * KT + r];
    }
  }
}

// Phase B: out[:,k] = V * out[:,k] in place. Tile = 16 matrix columns, natural
// [row][col] layout; staging is float4-native (ds_*_b128, bank-balanced).
__global__ __launch_bounds__(64) void rbs_cols(float* __restrict__ data,
                                               const float* __restrict__ ang) {
  __shared__ float tile[ROWS * KT];
  const int l = threadIdx.x;
  const int k0 = blockIdx.x * KT;
  float* base = data + (size_t)blockIdx.y * D * D + k0;
  const int kk = (l & 3) * 4, rl = l >> 2;
  const bool colok = (k0 + kk + 3) < D;          // last tile: cols 768..779 only

  for (int m = 0; m < 49; ++m) {
    const int rr = rl + 16 * m;
    if (rr < D && colok)
      *(float4*)(tile + rr * KT + kk) =
          *(const float4*)(base + (size_t)rr * D + kk);
  }
  __syncthreads();
  run_chain(tile, ang, l);
  __syncthreads();
  for (int m = 0; m < 49; ++m) {
    const int rr = rl + 16 * m;
    if (rr < D && colok)
      *(float4*)(base + (size_t)rr * D + kk) =
          *(const float4*)(tile + rr * KT + kk);
  }
}

extern "C" void kernel_launch(void* const* d_in, const int* in_sizes, int n_in,
                              void* d_out, int out_size, void* d_ws, size_t ws_size,
                              hipStream_t stream) {
  const float* rho = (const float*)d_in[0];   // [B, 780, 780] f32
  const float* ang = (const float*)d_in[1];   // [39] f32
  float* out = (float*)d_out;                 // [B, 780, 780] f32
  const int batch = in_sizes[0] / (D * D);    // 64
  const int ntiles = (D + KT - 1) / KT;       // 49

  rbs_rows<<<dim3(ntiles, batch), 64, 0, stream>>>(rho, ang, out);
  rbs_cols<<<dim3(ntiles, batch), 64, 0, stream>>>(out, ang);
}